// Round 2
// baseline (240.559 us; speedup 1.0000x reference)
//
#include <hip/hip_runtime.h>
#include <math.h>

#define B_    256
#define C_    22
#define T_    1000
#define NB_   6
#define E_    6
#define MNB_  48
#define POOL_ 125
#define TP_   8
#define NC_   9
#define FEAT_ 384   // MNB_*TP_

#define XSZ   1040   // logical [-20, 1019] with PAD=20; phys = logical + 20
#define PAD_  20

// ---------------------------------------------------------------------------
// Stage 1 (fused): 29-tap combined FIR+conv kernel, BN, ReLU, sconv-accum,
// pooled hp (B,NB,8) and gate-mean gm (B,NB).
// One block per (b, nb). 256 threads; thread owns 4 consecutive t (t0=4*tid).
// Double-buffered x row in LDS, 1 barrier per channel.
// ---------------------------------------------------------------------------
__global__ __launch_bounds__(256, 4) void fb_stage1(
    const float* __restrict__ x,
    const float* __restrict__ fir,
    const float* __restrict__ w3,
    const float* __restrict__ w5,
    const float* __restrict__ w7,
    const float* __restrict__ bn_g, const float* __restrict__ bn_b,
    const float* __restrict__ bn_m, const float* __restrict__ bn_v,
    const float* __restrict__ sconv_w,
    float* __restrict__ hp, float* __restrict__ gm)
{
    const int b   = blockIdx.x / NB_;
    const int nb  = blockIdx.x % NB_;
    const int tid = threadIdx.x;

    __shared__ float xs[2][XSZ];
    __shared__ float hrow[1000];
    __shared__ float firs[21];
    __shared__ float w3s[3], w5s[5], w7s[7];
    __shared__ float sws[22];
    __shared__ float sbn[2];
    __shared__ float psum[8];

    if (tid < 21)                 firs[tid]    = fir[nb*21 + tid];
    if (tid >= 32  && tid < 35)   w3s[tid-32]  = w3[nb*3 + (tid-32)];
    if (tid >= 64  && tid < 69)   w5s[tid-64]  = w5[nb*5 + (tid-64)];
    if (tid >= 96  && tid < 103)  w7s[tid-96]  = w7[nb*7 + (tid-96)];
    if (tid >= 128 && tid < 150)  sws[tid-128] = sconv_w[nb*C_ + (tid-128)];
    if (tid == 160) {
        float sc = bn_g[nb] * rsqrtf(bn_v[nb] + 1e-5f);
        sbn[0] = sc * (1.f/3.f);                 // folds the /3 of the triple-mean
        sbn[1] = bn_b[nb] - bn_m[nb] * sc;
    }
    // zero halos (both buffers): logical [-20,-1] and [1000,1019]
    if (tid < PAD_)               { xs[0][tid] = 0.f; xs[1][tid] = 0.f; }
    if (tid >= 224 && tid < 244)  { int k = 1020 + (tid - 224); xs[0][k] = 0.f; xs[1][k] = 0.f; }

    const bool act = (tid <= 249);
    const int  r   = (tid <= 82) ? 0 : ((tid <= 166) ? 1 : 2);
    const int  t0  = 4 * tid;
    const int  qq  = 3 * t0 - 1000 * r;          // window base (logical) = qq-13

    __syncthreads();

    // Build per-thread fused 29-tap kernel ck (once).
    float ck[29];
    if (act) {
        float weff[9];
        const float* wk = (r == 0) ? w3s : (r == 1 ? w5s : w7s);
        const int K  = (r == 0) ? 3 : (r == 1 ? 5 : 7);
        const int pk = K >> 1;
        #pragma unroll
        for (int oi = 0; oi < 9; ++oi) {
            const int o = oi - 3;
            float s = 0.f;
            #pragma unroll
            for (int k = 0; k < 7; ++k) {
                if (k < K) {
                    int j = o + pk - k;
                    if (j >= 0 && j < 3) s += wk[k];
                }
            }
            weff[oi] = s;
        }
        #pragma unroll
        for (int j = 0; j < 29; ++j) {
            float s = 0.f;
            #pragma unroll
            for (int oi = 0; oi < 9; ++oi) {
                const int i = j - oi;
                if (i >= 0 && i < 21) s = fmaf(weff[oi], firs[i], s);
            }
            ck[j] = s;
        }
    }

    const float* xrow = x + (size_t)(b * C_) * T_;
    float4 stg = make_float4(0.f, 0.f, 0.f, 0.f);
    if (tid < 250) stg = *(const float4*)(xrow + 4*tid);

    float acc0 = 0.f, acc1 = 0.f, acc2 = 0.f, acc3 = 0.f;

    #pragma unroll 1
    for (int c = 0; c < C_; ++c) {
        float* bw = xs[c & 1];
        if (tid < 250) *(float4*)&bw[PAD_ + 4*tid] = stg;
        __syncthreads();
        if (tid < 250 && c + 1 < C_)
            stg = *(const float4*)(xrow + (size_t)(c+1)*T_ + 4*tid);

        if (act) {
            // load 44-float window: logical [qq-16, qq+27] -> phys [qq+4, qq+47]
            float xw[44];
            const float* wbase = &bw[qq + 4];
            #pragma unroll
            for (int u = 0; u < 11; ++u)
                *(float4*)&xw[4*u] = *(const float4*)&wbase[4*u];

            float s0 = 0.f, s1 = 0.f, s2 = 0.f, s3 = 0.f;
            #pragma unroll
            for (int j = 0; j < 29; ++j) {
                const float cj = ck[j];
                s0 = fmaf(cj, xw[3  + j], s0);
                s1 = fmaf(cj, xw[6  + j], s1);
                s2 = fmaf(cj, xw[9  + j], s2);
                s3 = fmaf(cj, xw[12 + j], s3);
            }

            if (tid == 0) {
                // t=0: subtract w3[0]*xb'[-1] (xb zero-pad of 2nd conv)
                float xbm1 = 0.f;
                #pragma unroll
                for (int i = 11; i < 21; ++i) xbm1 = fmaf(firs[i], xw[i + 5], xbm1);
                s0 -= w3s[0] * xbm1;
            } else if (tid == 83) {
                // outputs 332,333 direct (region straddle); 334,335 fused (r=1) ok
                float xb[5];                       // xb'[995..999]
                #pragma unroll
                for (int d = 0; d < 5; ++d) {
                    float s = 0.f;
                    #pragma unroll
                    for (int i = 0; i < 21; ++i) s = fmaf(firs[i], bw[1005 + d + i], s);
                    xb[d] = s;
                }
                float xb0[4];                      // xb'[0..3] (from xw; qq=-4)
                #pragma unroll
                for (int p = 0; p < 4; ++p) {
                    float s = 0.f;
                    #pragma unroll
                    for (int i = 0; i < 21; ++i) s = fmaf(firs[i], xw[p + i + 10], s);
                    xb0[p] = s;
                }
                s0 = w3s[0]*(xb[0]+xb[1]+xb[2]) + w3s[1]*(xb[1]+xb[2]+xb[3])
                   + w3s[2]*(xb[2]+xb[3]+xb[4]);
                s1 = w3s[0]*xb[3] + w3s[1]*xb[4]
                   + w5s[2]*xb0[0] + w5s[3]*xb0[1] + w5s[4]*xb0[2]
                   + w5s[1]*xb0[0] + w5s[2]*xb0[1] + w5s[3]*xb0[2] + w5s[4]*xb0[3];
            } else if (tid == 166) {
                // outputs 664,665 fused (r=1) ok; 666,667 direct
                float xbU[4];                      // xb'[996..999] (from xw; qq=992)
                #pragma unroll
                for (int p = 0; p < 4; ++p) {
                    float s = 0.f;
                    #pragma unroll
                    for (int i = 0; i < 21; ++i) s = fmaf(firs[i], xw[10 + p + i], s);
                    xbU[p] = s;
                }
                float xb0[7];                      // xb'[0..6]
                #pragma unroll
                for (int p = 0; p < 7; ++p) {
                    float s = 0.f;
                    #pragma unroll
                    for (int i = 0; i < 21; ++i) s = fmaf(firs[i], bw[10 + p + i], s);
                    xb0[p] = s;
                }
                s2 = w5s[0]*xbU[0] + w5s[1]*xbU[1] + w5s[2]*xbU[2] + w5s[3]*xbU[3]
                   + w5s[0]*xbU[1] + w5s[1]*xbU[2] + w5s[2]*xbU[3]
                   + w7s[3]*xb0[0] + w7s[4]*xb0[1] + w7s[5]*xb0[2] + w7s[6]*xb0[3];
                s3 = w7s[2]*xb0[0] + w7s[3]*xb0[1] + w7s[4]*xb0[2] + w7s[5]*xb0[3] + w7s[6]*xb0[4]
                   + w7s[1]*xb0[0] + w7s[2]*xb0[1] + w7s[3]*xb0[2] + w7s[4]*xb0[3] + w7s[5]*xb0[4] + w7s[6]*xb0[5]
                   + w7s[0]*xb0[0] + w7s[1]*xb0[1] + w7s[2]*xb0[2] + w7s[3]*xb0[3] + w7s[4]*xb0[4] + w7s[5]*xb0[5] + w7s[6]*xb0[6];
            } else if (tid == 249) {
                // t=999: subtract weff7[3..5]*xb'[1000..1002]
                float xbA = 0.f, xbB = 0.f, xbC = 0.f;
                #pragma unroll
                for (int i = 0; i < 10; ++i) xbA = fmaf(firs[i], xw[31 + i], xbA);
                #pragma unroll
                for (int i = 0; i < 9;  ++i) xbB = fmaf(firs[i], xw[32 + i], xbB);
                #pragma unroll
                for (int i = 0; i < 8;  ++i) xbC = fmaf(firs[i], xw[33 + i], xbC);
                const float we3 = w7s[4] + w7s[5] + w7s[6];
                const float we4 = w7s[5] + w7s[6];
                const float we5 = w7s[6];
                s3 -= we3*xbA + we4*xbB + we5*xbC;
            }

            const float sc3 = sbn[0], bi = sbn[1], sw = sws[c];
            acc0 += fmaxf(fmaf(s0, sc3, bi), 0.f) * sw;
            acc1 += fmaxf(fmaf(s1, sc3, bi), 0.f) * sw;
            acc2 += fmaxf(fmaf(s2, sc3, bi), 0.f) * sw;
            acc3 += fmaxf(fmaf(s3, sc3, bi), 0.f) * sw;
        }
    }

    __syncthreads();
    if (act) *(float4*)&hrow[t0] = make_float4(acc0, acc1, acc2, acc3);
    __syncthreads();

    if (tid < TP_) {
        float s = 0.f;
        for (int j = 0; j < POOL_; ++j) s += hrow[tid*POOL_ + j];
        psum[tid] = s;
        hp[(b*NB_ + nb)*TP_ + tid] = s * (1.f / POOL_);
    }
    __syncthreads();
    if (tid == 0) {
        float s = 0.f;
        for (int p = 0; p < TP_; ++p) s += psum[p];
        gm[b*NB_ + nb] = s * (1.f / T_);
    }
}

// ---------------------------------------------------------------------------
// Stage 2: gate (softmax + top-3 + renorm), experts + EBN + ReLU + mix,
//          FC + log_softmax.  One block (64 thr) per batch element.
// ---------------------------------------------------------------------------
__global__ __launch_bounds__(64) void fb_stage2(
    const float* __restrict__ hp, const float* __restrict__ gm,
    const float* __restrict__ gate_w, const float* __restrict__ gate_b,
    const float* __restrict__ exp_w,  const float* __restrict__ exp_b,
    const float* __restrict__ ebn_g,  const float* __restrict__ ebn_b,
    const float* __restrict__ ebn_m,  const float* __restrict__ ebn_v,
    const float* __restrict__ fc_w,   const float* __restrict__ fc_b,
    float* __restrict__ feats_out, float* __restrict__ logp_out)
{
    const int b   = blockIdx.x;
    const int tid = threadIdx.x;

    __shared__ float lg[MNB_];
    __shared__ float gsh[E_];
    __shared__ float hps[MNB_];
    __shared__ float fsh[FEAT_];
    __shared__ float lo[NC_];

    if (tid < MNB_) {
        hps[tid] = hp[b*MNB_ + tid];
        float s = gate_b[tid];
        for (int c = 0; c < NB_; ++c) s += gm[b*NB_ + c] * gate_w[tid*NB_ + c];
        lg[tid] = s;
    }
    __syncthreads();

    if (tid == 0) {
        float mx = lg[0];
        for (int i = 1; i < MNB_; ++i) mx = fmaxf(mx, lg[i]);
        for (int i = 0; i < MNB_; ++i) lg[i] = expf(lg[i] - mx);
        int i1 = 0, i2 = -1, i3 = -1;
        float b1 = -1.f, b2 = -1.f, b3 = -1.f;
        for (int i = 0; i < MNB_; ++i) if (lg[i] > b1) { b1 = lg[i]; i1 = i; }
        for (int i = 0; i < MNB_; ++i) if (i != i1 && lg[i] > b2) { b2 = lg[i]; i2 = i; }
        for (int i = 0; i < MNB_; ++i) if (i != i1 && i != i2 && lg[i] > b3) { b3 = lg[i]; i3 = i; }
        const float s3 = lg[i1] + lg[i2] + lg[i3];
        for (int j = 0; j < E_; ++j) gsh[j] = 0.f;
        if (i1 < E_) gsh[i1] = lg[i1] / s3;
        if (i2 < E_) gsh[i2] = lg[i2] / s3;
        if (i3 < E_) gsh[i3] = lg[i3] / s3;
    }
    __syncthreads();

    #pragma unroll
    for (int rr = 0; rr < FEAT_/64; ++rr) {
        const int idx = tid + rr*64;        // 0..383
        const int o = idx >> 3, p = idx & 7;
        float outv = 0.f;
        #pragma unroll
        for (int e = 0; e < E_; ++e) {
            const int eo = e*MNB_ + o;
            float acc = exp_b[eo];
            #pragma unroll
            for (int c = 0; c < NB_; ++c)
                acc += hps[c*TP_ + p] * exp_w[eo*NB_ + c];
            const float esc = ebn_g[eo] * rsqrtf(ebn_v[eo] + 1e-5f);
            float v = fmaf(acc - ebn_m[eo], esc, ebn_b[eo]);
            v = fmaxf(v, 0.f);
            outv += gsh[e] * v;
        }
        fsh[idx] = outv;
        feats_out[b*FEAT_ + idx] = outv;
    }
    __syncthreads();

    if (tid < NC_) {
        float s = fc_b[tid];
        for (int i = 0; i < FEAT_; ++i) s += fsh[i] * fc_w[tid*FEAT_ + i];
        lo[tid] = s;
    }
    __syncthreads();

    if (tid == 0) {
        float mx = lo[0];
        for (int k = 1; k < NC_; ++k) mx = fmaxf(mx, lo[k]);
        float Z = 0.f;
        for (int k = 0; k < NC_; ++k) Z += expf(lo[k] - mx);
        const float lse = mx + logf(Z);
        for (int k = 0; k < NC_; ++k) logp_out[b*NC_ + k] = lo[k] - lse;
    }
}

extern "C" void kernel_launch(void* const* d_in, const int* in_sizes, int n_in,
                              void* d_out, int out_size, void* d_ws, size_t ws_size,
                              hipStream_t stream) {
    const float* x       = (const float*)d_in[0];
    const float* fir     = (const float*)d_in[1];
    const float* w3      = (const float*)d_in[2];
    const float* w5      = (const float*)d_in[3];
    const float* w7      = (const float*)d_in[4];
    const float* bn1_g   = (const float*)d_in[5];
    const float* bn1_b   = (const float*)d_in[6];
    const float* bn1_m   = (const float*)d_in[7];
    const float* bn1_v   = (const float*)d_in[8];
    const float* sconv_w = (const float*)d_in[9];
    const float* gate_w  = (const float*)d_in[10];
    const float* gate_b  = (const float*)d_in[11];
    const float* exp_w   = (const float*)d_in[12];
    const float* exp_b   = (const float*)d_in[13];
    const float* ebn_g   = (const float*)d_in[14];
    const float* ebn_b   = (const float*)d_in[15];
    const float* ebn_m   = (const float*)d_in[16];
    const float* ebn_v   = (const float*)d_in[17];
    const float* fc_w    = (const float*)d_in[18];
    const float* fc_b    = (const float*)d_in[19];

    float* out       = (float*)d_out;
    float* feats_out = out;                     // (256, 384)
    float* logp_out  = out + B_ * FEAT_;        // (256, 9)

    float* hp  = (float*)d_ws;                  // (256, 48)
    float* gmv = hp + B_ * MNB_;                // (256, 6)

    fb_stage1<<<B_ * NB_, 256, 0, stream>>>(x, fir, w3, w5, w7,
                                            bn1_g, bn1_b, bn1_m, bn1_v,
                                            sconv_w, hp, gmv);
    fb_stage2<<<B_, 64, 0, stream>>>(hp, gmv, gate_w, gate_b,
                                     exp_w, exp_b, ebn_g, ebn_b, ebn_m, ebn_v,
                                     fc_w, fc_b, feats_out, logp_out);
}

// Round 3
// 224.143 us; speedup vs baseline: 1.0732x; 1.0732x over previous
//
#include <hip/hip_runtime.h>
#include <math.h>

#define B_    256
#define C_    22
#define T_    1000
#define NB_   6
#define E_    6
#define MNB_  48
#define POOL_ 125
#define TP_   8
#define NC_   9
#define FEAT_ 384   // MNB_*TP_

#define XSZ   1040   // logical [-20, 1019] with PAD=20; phys = logical + 20
#define PAD_  20

// ---------------------------------------------------------------------------
// Stage 1 (fused): 29-tap combined FIR+conv kernel, BN, ReLU, sconv-accum,
// pooled hp (B,NB,8) and gate-mean gm (B,NB).
// One block per (b, nb). 256 threads; thread owns 4 consecutive t (t0=4*tid).
// Double-buffered x row in LDS, 1 barrier per channel.
// __launch_bounds__(256,2): VGPR cap 128 — (256,4) capped at 64 and spilled
// ~186MB/launch to scratch (round-2 post-mortem).
// ---------------------------------------------------------------------------
__global__ __launch_bounds__(256, 2) void fb_stage1(
    const float* __restrict__ x,
    const float* __restrict__ fir,
    const float* __restrict__ w3,
    const float* __restrict__ w5,
    const float* __restrict__ w7,
    const float* __restrict__ bn_g, const float* __restrict__ bn_b,
    const float* __restrict__ bn_m, const float* __restrict__ bn_v,
    const float* __restrict__ sconv_w,
    float* __restrict__ hp, float* __restrict__ gm)
{
    const int b   = blockIdx.x / NB_;
    const int nb  = blockIdx.x % NB_;
    const int tid = threadIdx.x;

    __shared__ float xs[2][XSZ];
    __shared__ float hrow[1000];
    __shared__ float firs[21];
    __shared__ float w3s[3], w5s[5], w7s[7];
    __shared__ float sws[22];
    __shared__ float sbn[2];
    __shared__ float psum[8];

    if (tid < 21)                 firs[tid]    = fir[nb*21 + tid];
    if (tid >= 32  && tid < 35)   w3s[tid-32]  = w3[nb*3 + (tid-32)];
    if (tid >= 64  && tid < 69)   w5s[tid-64]  = w5[nb*5 + (tid-64)];
    if (tid >= 96  && tid < 103)  w7s[tid-96]  = w7[nb*7 + (tid-96)];
    if (tid >= 128 && tid < 150)  sws[tid-128] = sconv_w[nb*C_ + (tid-128)];
    if (tid == 160) {
        float sc = bn_g[nb] * rsqrtf(bn_v[nb] + 1e-5f);
        sbn[0] = sc * (1.f/3.f);                 // folds the /3 of the triple-mean
        sbn[1] = bn_b[nb] - bn_m[nb] * sc;
    }
    // zero halos (both buffers): logical [-20,-1] and [1000,1019]
    if (tid < PAD_)               { xs[0][tid] = 0.f; xs[1][tid] = 0.f; }
    if (tid >= 224 && tid < 244)  { int k = 1020 + (tid - 224); xs[0][k] = 0.f; xs[1][k] = 0.f; }

    const bool act = (tid <= 249);
    const int  r   = (tid <= 82) ? 0 : ((tid <= 166) ? 1 : 2);
    const int  t0  = 4 * tid;
    const int  qq  = 3 * t0 - 1000 * r;          // window base (logical) = qq-13

    __syncthreads();

    // Build per-thread fused 29-tap kernel ck (once).
    float ck[29];
    if (act) {
        float weff[9];
        const float* wk = (r == 0) ? w3s : (r == 1 ? w5s : w7s);
        const int K  = (r == 0) ? 3 : (r == 1 ? 5 : 7);
        const int pk = K >> 1;
        #pragma unroll
        for (int oi = 0; oi < 9; ++oi) {
            const int o = oi - 3;
            float s = 0.f;
            #pragma unroll
            for (int k = 0; k < 7; ++k) {
                if (k < K) {
                    int j = o + pk - k;
                    if (j >= 0 && j < 3) s += wk[k];
                }
            }
            weff[oi] = s;
        }
        #pragma unroll
        for (int j = 0; j < 29; ++j) {
            float s = 0.f;
            #pragma unroll
            for (int oi = 0; oi < 9; ++oi) {
                const int i = j - oi;
                if (i >= 0 && i < 21) s = fmaf(weff[oi], firs[i], s);
            }
            ck[j] = s;
        }
    }

    const float* xrow = x + (size_t)(b * C_) * T_;
    float4 stg = make_float4(0.f, 0.f, 0.f, 0.f);
    if (tid < 250) stg = *(const float4*)(xrow + 4*tid);

    float acc0 = 0.f, acc1 = 0.f, acc2 = 0.f, acc3 = 0.f;

    #pragma unroll 1
    for (int c = 0; c < C_; ++c) {
        float* bw = xs[c & 1];
        if (tid < 250) *(float4*)&bw[PAD_ + 4*tid] = stg;
        __syncthreads();
        if (tid < 250 && c + 1 < C_)
            stg = *(const float4*)(xrow + (size_t)(c+1)*T_ + 4*tid);

        if (act) {
            // load 44-float window: logical [qq-16, qq+27] -> phys [qq+4, qq+47]
            float xw[44];
            const float* wbase = &bw[qq + 4];
            #pragma unroll
            for (int u = 0; u < 11; ++u)
                *(float4*)&xw[4*u] = *(const float4*)&wbase[4*u];

            float s0 = 0.f, s1 = 0.f, s2 = 0.f, s3 = 0.f;
            #pragma unroll
            for (int j = 0; j < 29; ++j) {
                const float cj = ck[j];
                s0 = fmaf(cj, xw[3  + j], s0);
                s1 = fmaf(cj, xw[6  + j], s1);
                s2 = fmaf(cj, xw[9  + j], s2);
                s3 = fmaf(cj, xw[12 + j], s3);
            }

            if (tid == 0) {
                // t=0: subtract w3[0]*xb'[-1] (xb zero-pad of 2nd conv)
                float xbm1 = 0.f;
                #pragma unroll
                for (int i = 11; i < 21; ++i) xbm1 = fmaf(firs[i], xw[i + 5], xbm1);
                s0 -= w3s[0] * xbm1;
            } else if (tid == 83) {
                // outputs 332,333 direct (region straddle); 334,335 fused (r=1) ok
                float xb[5];                       // xb'[995..999]
                #pragma unroll
                for (int d = 0; d < 5; ++d) {
                    float s = 0.f;
                    #pragma unroll
                    for (int i = 0; i < 21; ++i) s = fmaf(firs[i], bw[1005 + d + i], s);
                    xb[d] = s;
                }
                float xb0[4];                      // xb'[0..3] (from xw; qq=-4)
                #pragma unroll
                for (int p = 0; p < 4; ++p) {
                    float s = 0.f;
                    #pragma unroll
                    for (int i = 0; i < 21; ++i) s = fmaf(firs[i], xw[p + i + 10], s);
                    xb0[p] = s;
                }
                s0 = w3s[0]*(xb[0]+xb[1]+xb[2]) + w3s[1]*(xb[1]+xb[2]+xb[3])
                   + w3s[2]*(xb[2]+xb[3]+xb[4]);
                s1 = w3s[0]*xb[3] + w3s[1]*xb[4]
                   + w5s[2]*xb0[0] + w5s[3]*xb0[1] + w5s[4]*xb0[2]
                   + w5s[1]*xb0[0] + w5s[2]*xb0[1] + w5s[3]*xb0[2] + w5s[4]*xb0[3];
            } else if (tid == 166) {
                // outputs 664,665 fused (r=1) ok; 666,667 direct
                float xbU[4];                      // xb'[996..999] (from xw; qq=992)
                #pragma unroll
                for (int p = 0; p < 4; ++p) {
                    float s = 0.f;
                    #pragma unroll
                    for (int i = 0; i < 21; ++i) s = fmaf(firs[i], xw[10 + p + i], s);
                    xbU[p] = s;
                }
                float xb0[7];                      // xb'[0..6]
                #pragma unroll
                for (int p = 0; p < 7; ++p) {
                    float s = 0.f;
                    #pragma unroll
                    for (int i = 0; i < 21; ++i) s = fmaf(firs[i], bw[10 + p + i], s);
                    xb0[p] = s;
                }
                s2 = w5s[0]*xbU[0] + w5s[1]*xbU[1] + w5s[2]*xbU[2] + w5s[3]*xbU[3]
                   + w5s[0]*xbU[1] + w5s[1]*xbU[2] + w5s[2]*xbU[3]
                   + w7s[3]*xb0[0] + w7s[4]*xb0[1] + w7s[5]*xb0[2] + w7s[6]*xb0[3];
                s3 = w7s[2]*xb0[0] + w7s[3]*xb0[1] + w7s[4]*xb0[2] + w7s[5]*xb0[3] + w7s[6]*xb0[4]
                   + w7s[1]*xb0[0] + w7s[2]*xb0[1] + w7s[3]*xb0[2] + w7s[4]*xb0[3] + w7s[5]*xb0[4] + w7s[6]*xb0[5]
                   + w7s[0]*xb0[0] + w7s[1]*xb0[1] + w7s[2]*xb0[2] + w7s[3]*xb0[3] + w7s[4]*xb0[4] + w7s[5]*xb0[5] + w7s[6]*xb0[6];
            } else if (tid == 249) {
                // t=999: subtract weff7[3..5]*xb'[1000..1002]
                float xbA = 0.f, xbB = 0.f, xbC = 0.f;
                #pragma unroll
                for (int i = 0; i < 10; ++i) xbA = fmaf(firs[i], xw[31 + i], xbA);
                #pragma unroll
                for (int i = 0; i < 9;  ++i) xbB = fmaf(firs[i], xw[32 + i], xbB);
                #pragma unroll
                for (int i = 0; i < 8;  ++i) xbC = fmaf(firs[i], xw[33 + i], xbC);
                const float we3 = w7s[4] + w7s[5] + w7s[6];
                const float we4 = w7s[5] + w7s[6];
                const float we5 = w7s[6];
                s3 -= we3*xbA + we4*xbB + we5*xbC;
            }

            const float sc3 = sbn[0], bi = sbn[1], sw = sws[c];
            acc0 += fmaxf(fmaf(s0, sc3, bi), 0.f) * sw;
            acc1 += fmaxf(fmaf(s1, sc3, bi), 0.f) * sw;
            acc2 += fmaxf(fmaf(s2, sc3, bi), 0.f) * sw;
            acc3 += fmaxf(fmaf(s3, sc3, bi), 0.f) * sw;
        }
    }

    __syncthreads();
    if (act) *(float4*)&hrow[t0] = make_float4(acc0, acc1, acc2, acc3);
    __syncthreads();

    if (tid < TP_) {
        float s = 0.f;
        for (int j = 0; j < POOL_; ++j) s += hrow[tid*POOL_ + j];
        psum[tid] = s;
        hp[(b*NB_ + nb)*TP_ + tid] = s * (1.f / POOL_);
    }
    __syncthreads();
    if (tid == 0) {
        float s = 0.f;
        for (int p = 0; p < TP_; ++p) s += psum[p];
        gm[b*NB_ + nb] = s * (1.f / T_);
    }
}

// ---------------------------------------------------------------------------
// Stage 2: gate (softmax + top-3 + renorm), experts + EBN + ReLU + mix,
//          FC + log_softmax.  One block (64 thr) per batch element.
// ---------------------------------------------------------------------------
__global__ __launch_bounds__(64) void fb_stage2(
    const float* __restrict__ hp, const float* __restrict__ gm,
    const float* __restrict__ gate_w, const float* __restrict__ gate_b,
    const float* __restrict__ exp_w,  const float* __restrict__ exp_b,
    const float* __restrict__ ebn_g,  const float* __restrict__ ebn_b,
    const float* __restrict__ ebn_m,  const float* __restrict__ ebn_v,
    const float* __restrict__ fc_w,   const float* __restrict__ fc_b,
    float* __restrict__ feats_out, float* __restrict__ logp_out)
{
    const int b   = blockIdx.x;
    const int tid = threadIdx.x;

    __shared__ float lg[MNB_];
    __shared__ float gsh[E_];
    __shared__ float hps[MNB_];
    __shared__ float fsh[FEAT_];
    __shared__ float lo[NC_];

    if (tid < MNB_) {
        hps[tid] = hp[b*MNB_ + tid];
        float s = gate_b[tid];
        for (int c = 0; c < NB_; ++c) s += gm[b*NB_ + c] * gate_w[tid*NB_ + c];
        lg[tid] = s;
    }
    __syncthreads();

    if (tid == 0) {
        float mx = lg[0];
        for (int i = 1; i < MNB_; ++i) mx = fmaxf(mx, lg[i]);
        for (int i = 0; i < MNB_; ++i) lg[i] = expf(lg[i] - mx);
        int i1 = 0, i2 = -1, i3 = -1;
        float b1 = -1.f, b2 = -1.f, b3 = -1.f;
        for (int i = 0; i < MNB_; ++i) if (lg[i] > b1) { b1 = lg[i]; i1 = i; }
        for (int i = 0; i < MNB_; ++i) if (i != i1 && lg[i] > b2) { b2 = lg[i]; i2 = i; }
        for (int i = 0; i < MNB_; ++i) if (i != i1 && i != i2 && lg[i] > b3) { b3 = lg[i]; i3 = i; }
        const float s3 = lg[i1] + lg[i2] + lg[i3];
        for (int j = 0; j < E_; ++j) gsh[j] = 0.f;
        if (i1 < E_) gsh[i1] = lg[i1] / s3;
        if (i2 < E_) gsh[i2] = lg[i2] / s3;
        if (i3 < E_) gsh[i3] = lg[i3] / s3;
    }
    __syncthreads();

    #pragma unroll
    for (int rr = 0; rr < FEAT_/64; ++rr) {
        const int idx = tid + rr*64;        // 0..383
        const int o = idx >> 3, p = idx & 7;
        float outv = 0.f;
        #pragma unroll
        for (int e = 0; e < E_; ++e) {
            const int eo = e*MNB_ + o;
            float acc = exp_b[eo];
            #pragma unroll
            for (int c = 0; c < NB_; ++c)
                acc += hps[c*TP_ + p] * exp_w[eo*NB_ + c];
            const float esc = ebn_g[eo] * rsqrtf(ebn_v[eo] + 1e-5f);
            float v = fmaf(acc - ebn_m[eo], esc, ebn_b[eo]);
            v = fmaxf(v, 0.f);
            outv += gsh[e] * v;
        }
        fsh[idx] = outv;
        feats_out[b*FEAT_ + idx] = outv;
    }
    __syncthreads();

    if (tid < NC_) {
        float s = fc_b[tid];
        for (int i = 0; i < FEAT_; ++i) s += fsh[i] * fc_w[tid*FEAT_ + i];
        lo[tid] = s;
    }
    __syncthreads();

    if (tid == 0) {
        float mx = lo[0];
        for (int k = 1; k < NC_; ++k) mx = fmaxf(mx, lo[k]);
        float Z = 0.f;
        for (int k = 0; k < NC_; ++k) Z += expf(lo[k] - mx);
        const float lse = mx + logf(Z);
        for (int k = 0; k < NC_; ++k) logp_out[b*NC_ + k] = lo[k] - lse;
    }
}

extern "C" void kernel_launch(void* const* d_in, const int* in_sizes, int n_in,
                              void* d_out, int out_size, void* d_ws, size_t ws_size,
                              hipStream_t stream) {
    const float* x       = (const float*)d_in[0];
    const float* fir     = (const float*)d_in[1];
    const float* w3      = (const float*)d_in[2];
    const float* w5      = (const float*)d_in[3];
    const float* w7      = (const float*)d_in[4];
    const float* bn1_g   = (const float*)d_in[5];
    const float* bn1_b   = (const float*)d_in[6];
    const float* bn1_m   = (const float*)d_in[7];
    const float* bn1_v   = (const float*)d_in[8];
    const float* sconv_w = (const float*)d_in[9];
    const float* gate_w  = (const float*)d_in[10];
    const float* gate_b  = (const float*)d_in[11];
    const float* exp_w   = (const float*)d_in[12];
    const float* exp_b   = (const float*)d_in[13];
    const float* ebn_g   = (const float*)d_in[14];
    const float* ebn_b   = (const float*)d_in[15];
    const float* ebn_m   = (const float*)d_in[16];
    const float* ebn_v   = (const float*)d_in[17];
    const float* fc_w    = (const float*)d_in[18];
    const float* fc_b    = (const float*)d_in[19];

    float* out       = (float*)d_out;
    float* feats_out = out;                     // (256, 384)
    float* logp_out  = out + B_ * FEAT_;        // (256, 9)

    float* hp  = (float*)d_ws;                  // (256, 48)
    float* gmv = hp + B_ * MNB_;                // (256, 6)

    fb_stage1<<<B_ * NB_, 256, 0, stream>>>(x, fir, w3, w5, w7,
                                            bn1_g, bn1_b, bn1_m, bn1_v,
                                            sconv_w, hp, gmv);
    fb_stage2<<<B_, 64, 0, stream>>>(hp, gmv, gate_w, gate_b,
                                     exp_w, exp_b, ebn_g, ebn_b, ebn_m, ebn_v,
                                     fc_w, fc_b, feats_out, logp_out);
}